// Round 2
// baseline (32.296 us; speedup 1.0000x reference)
//
#include <hip/hip_runtime.h>

#define LENGTH   256
#define VOLUME   (LENGTH * LENGTH)
#define N_STATES 256
#define ACTION_SHIFT_F 131072.0f   // 2 * BETA * VOLUME, BETA = 1
#define BPS      8                 // blocks per state
#define THREADS  256
#define ROWS_PER_WAVE 8            // 4 waves/block * 8 rows = 32 rows/block; 8 blocks/state = 256 rows

__global__ __launch_bounds__(THREADS)
void action_kernel(const float* __restrict__ state, float* __restrict__ out)
{
    const int blk = blockIdx.x;
    const int n   = blk >> 3;      // state index
    const int b   = blk & 7;       // band within state
    const float* __restrict__ theta = state + (size_t)n * (2 * VOLUME);
    const float* __restrict__ phi   = theta + VOLUME;

    const int wave = threadIdx.x >> 6;
    const int lane = threadIdx.x & 63;
    const int srcLane = (lane + 63) & 63;   // lane-1 with wrap (col 0's left = col 255)

    const int r0 = b * (BPS * 4) + wave * ROWS_PER_WAVE;  // 32 rows/block, 8 rows/wave
    const int c  = lane * 4;                               // 4 contiguous cols per lane

    // ---- prime: previous row (wraps at lattice edge), becomes "up" for row r0
    float sU[4], cU[4], pU[4];
    {
        const int rp = (r0 + LENGTH - 1) & (LENGTH - 1);
        const float4 tp = *reinterpret_cast<const float4*>(theta + rp * LENGTH + c);
        const float4 pp = *reinterpret_cast<const float4*>(phi   + rp * LENGTH + c);
        const float tv[4] = {tp.x, tp.y, tp.z, tp.w};
        const float pv[4] = {pp.x, pp.y, pp.z, pp.w};
        #pragma unroll
        for (int j = 0; j < 4; ++j) {
            __sincosf(tv[j], &sU[j], &cU[j]);
            pU[j] = pv[j];
        }
    }

    float acc = 0.0f;
    #pragma unroll
    for (int k = 0; k < ROWS_PER_WAVE; ++k) {
        const int r = r0 + k;
        const float4 t = *reinterpret_cast<const float4*>(theta + r * LENGTH + c);
        const float4 p = *reinterpret_cast<const float4*>(phi   + r * LENGTH + c);
        const float tv[4] = {t.x, t.y, t.z, t.w};
        float pv[4] = {p.x, p.y, p.z, p.w};

        float s[4], cc[4];
        #pragma unroll
        for (int j = 0; j < 4; ++j)
            __sincosf(tv[j], &s[j], &cc[j]);

        // left-neighbor of element 0: lane-1's element 3 (same row), via shuffle
        const float sL = __shfl(s[3],  srcLane, 64);
        const float cL = __shfl(cc[3], srcLane, 64);
        const float pL = __shfl(pv[3], srcLane, 64);

        // vertical (up) interactions — up sincos reused from previous iteration
        #pragma unroll
        for (int j = 0; j < 4; ++j)
            acc += cU[j] * cc[j] + sU[j] * s[j] * __cosf(pU[j] - pv[j]);

        // horizontal (left) interactions
        acc += cL * cc[0] + sL * s[0] * __cosf(pL - pv[0]);
        #pragma unroll
        for (int j = 1; j < 4; ++j)
            acc += cc[j-1] * cc[j] + s[j-1] * s[j] * __cosf(pv[j-1] - pv[j]);

        // current row becomes "up" for the next row
        #pragma unroll
        for (int j = 0; j < 4; ++j) { sU[j] = s[j]; cU[j] = cc[j]; pU[j] = pv[j]; }
    }

    // ---- block reduction: 64-lane butterfly, then cross-wave via LDS
    #pragma unroll
    for (int off = 32; off >= 1; off >>= 1)
        acc += __shfl_down(acc, off, 64);

    __shared__ float red[THREADS / 64];
    if (lane == 0) red[wave] = acc;
    __syncthreads();
    if (threadIdx.x == 0) {
        float ssum = red[0] + red[1] + red[2] + red[3];
        // out was memset to 0; block 0 of each state contributes the shift
        atomicAdd(out + n, (b == 0 ? ACTION_SHIFT_F : 0.0f) - ssum);
    }
}

extern "C" void kernel_launch(void* const* d_in, const int* in_sizes, int n_in,
                              void* d_out, int out_size, void* d_ws, size_t ws_size,
                              hipStream_t stream)
{
    const float* state = (const float*)d_in[0];
    // d_in[1] (shift table) is the fixed torus-neighbor map; computed analytically.
    float* out = (float*)d_out;

    hipMemsetAsync(out, 0, (size_t)out_size * sizeof(float), stream);
    action_kernel<<<dim3(N_STATES * BPS), dim3(THREADS), 0, stream>>>(state, out);
}

// Round 3
// 32.090 us; speedup vs baseline: 1.0064x; 1.0064x over previous
//
#include <hip/hip_runtime.h>

#define LENGTH   256
#define VOLUME   (LENGTH * LENGTH)
#define N_STATES 256
#define ACTION_SHIFT_F 131072.0f   // 2 * BETA * VOLUME, BETA = 1
#define BPS      8                 // blocks per state
#define EPB      (VOLUME / BPS)    // 8192 elements per block
#define THREADS  256
#define NGROUPS  (EPB / (4 * THREADS))   // 8 float4-groups per thread

// Load one group's operands: center theta/phi, up-row theta/phi, left-scalar theta/phi.
#define LOAD_GROUP(IT, TC, PC, TU, PU, TL, PL) do {                         \
    const int _i  = base + (((IT) * THREADS) + (int)threadIdx.x) * 4;       \
    TC = *reinterpret_cast<const float4*>(theta + _i);                      \
    PC = *reinterpret_cast<const float4*>(phi   + _i);                      \
    const int _up = (_i >= LENGTH) ? (_i - LENGTH) : (_i + (VOLUME - LENGTH)); \
    TU = *reinterpret_cast<const float4*>(theta + _up);                     \
    PU = *reinterpret_cast<const float4*>(phi   + _up);                     \
    const int _c0 = _i & (LENGTH - 1);                                      \
    const int _l0 = (_c0 == 0) ? (_i + (LENGTH - 1)) : (_i - 1);            \
    TL = theta[_l0];                                                        \
    PL = phi[_l0];                                                          \
} while (0)

__global__ __launch_bounds__(THREADS)
void action_kernel(const float* __restrict__ state, float* __restrict__ out)
{
    const int blk = blockIdx.x;
    const int n   = blk >> 3;      // state index
    const int b   = blk & 7;       // chunk within state
    const float* __restrict__ theta = state + (size_t)n * (2 * VOLUME);
    const float* __restrict__ phi   = theta + VOLUME;
    const int base = b * EPB;

    float acc0 = 0.0f;   // vertical interactions
    float acc1 = 0.0f;   // horizontal interactions

    float4 tc, pc, tu, pu; float tl, pl;
    LOAD_GROUP(0, tc, pc, tu, pu, tl, pl);

    #pragma unroll
    for (int it = 0; it < NGROUPS; ++it) {
        // consume current group's registers; issue next group's loads first
        const float4 TC = tc, PC = pc, TU = tu, PU = pu;
        const float  TL = tl, PL = pl;
        if (it < NGROUPS - 1)
            LOAD_GROUP(it + 1, tc, pc, tu, pu, tl, pl);

        const float tcv[4] = {TC.x, TC.y, TC.z, TC.w};
        const float pcv[4] = {PC.x, PC.y, PC.z, PC.w};
        const float tuv[4] = {TU.x, TU.y, TU.z, TU.w};
        const float puv[4] = {PU.x, PU.y, PU.z, PU.w};

        float sc[4], cc[4], su[4], cu[4];
        #pragma unroll
        for (int j = 0; j < 4; ++j) {
            __sincosf(tcv[j], &sc[j], &cc[j]);
            __sincosf(tuv[j], &su[j], &cu[j]);
        }
        float sl, cl;
        __sincosf(TL, &sl, &cl);

        // vertical (up) interactions
        #pragma unroll
        for (int j = 0; j < 4; ++j)
            acc0 += cu[j] * cc[j] + su[j] * sc[j] * __cosf(puv[j] - pcv[j]);

        // horizontal (left) interactions; reuse center sincos as neighbor
        acc1 += cl * cc[0] + sl * sc[0] * __cosf(PL - pcv[0]);
        #pragma unroll
        for (int j = 1; j < 4; ++j)
            acc1 += cc[j-1] * cc[j] + sc[j-1] * sc[j] * __cosf(pcv[j-1] - pcv[j]);
    }

    float acc = acc0 + acc1;

    // wave (64-lane) butterfly reduce, then cross-wave via LDS
    #pragma unroll
    for (int off = 32; off >= 1; off >>= 1)
        acc += __shfl_down(acc, off, 64);

    __shared__ float red[THREADS / 64];
    const int wave = threadIdx.x >> 6;
    const int lane = threadIdx.x & 63;
    if (lane == 0) red[wave] = acc;
    __syncthreads();
    if (threadIdx.x == 0) {
        const float ssum = red[0] + red[1] + red[2] + red[3];
        // out was memset to 0; block 0 of each state contributes the shift
        atomicAdd(out + n, (b == 0 ? ACTION_SHIFT_F : 0.0f) - ssum);
    }
}

extern "C" void kernel_launch(void* const* d_in, const int* in_sizes, int n_in,
                              void* d_out, int out_size, void* d_ws, size_t ws_size,
                              hipStream_t stream)
{
    const float* state = (const float*)d_in[0];
    // d_in[1] (shift table) is the fixed torus-neighbor map; computed analytically.
    float* out = (float*)d_out;

    hipMemsetAsync(out, 0, (size_t)out_size * sizeof(float), stream);
    action_kernel<<<dim3(N_STATES * BPS), dim3(THREADS), 0, stream>>>(state, out);
}

// Round 4
// 31.289 us; speedup vs baseline: 1.0322x; 1.0256x over previous
//
#include <hip/hip_runtime.h>

#define LENGTH   256
#define VOLUME   (LENGTH * LENGTH)
#define N_STATES 256
#define ACTION_SHIFT_F 131072.0f   // 2 * BETA * VOLUME, BETA = 1
#define THREADS  1024
#define NWAVES   (THREADS / 64)    // 16 waves per block
#define RPW      (LENGTH / NWAVES) // 16 rows per wave

// One block per state (256 blocks on 256 CUs, no tail, no cross-block fold).
// Each wave owns a 16-row band; each lane owns 4 contiguous columns.
// Vertical neighbor = previous row's sincos kept in registers.
// Horizontal neighbor = lane-1's raw loaded value via shuffle (no
// sincos->shuffle dependency: shuffle only the just-loaded theta/phi).
__global__ __launch_bounds__(THREADS, 1)
void action_kernel(const float* __restrict__ state, float* __restrict__ out)
{
    const int n = blockIdx.x;
    const float* __restrict__ theta = state + (size_t)n * (2 * VOLUME);
    const float* __restrict__ phi   = theta + VOLUME;

    const int wave    = threadIdx.x >> 6;
    const int lane    = threadIdx.x & 63;
    const int srcLane = (lane + 63) & 63;   // lane-1 wrap: col 0's left = col 255
    const int r0      = wave * RPW;
    const int c       = lane * 4;

    // ---- prime: row r0-1 (wraps), becomes "up" for row r0
    float sU[4], cU[4], pU[4];
    {
        const int rp = (r0 + LENGTH - 1) & (LENGTH - 1);
        const float4 tp = *reinterpret_cast<const float4*>(theta + rp * LENGTH + c);
        const float4 pp = *reinterpret_cast<const float4*>(phi   + rp * LENGTH + c);
        const float tv[4] = {tp.x, tp.y, tp.z, tp.w};
        #pragma unroll
        for (int j = 0; j < 4; ++j) __sincosf(tv[j], &sU[j], &cU[j]);
        pU[0] = pp.x; pU[1] = pp.y; pU[2] = pp.z; pU[3] = pp.w;
    }

    // ---- 2-deep pipelined row march
    float4 tc = *reinterpret_cast<const float4*>(theta + r0 * LENGTH + c);
    float4 pc = *reinterpret_cast<const float4*>(phi   + r0 * LENGTH + c);

    float acc0 = 0.0f, acc1 = 0.0f;
    #pragma unroll 2
    for (int k = 0; k < RPW; ++k) {
        const float4 TC = tc, PC = pc;
        if (k < RPW - 1) {
            const int r = r0 + k + 1;
            tc = *reinterpret_cast<const float4*>(theta + r * LENGTH + c);
            pc = *reinterpret_cast<const float4*>(phi   + r * LENGTH + c);
        }

        // left neighbor of element 0: lane-1's element 3, raw values
        const float TL = __shfl(TC.w, srcLane, 64);
        const float PL = __shfl(PC.w, srcLane, 64);

        const float tv[4] = {TC.x, TC.y, TC.z, TC.w};
        const float pv[4] = {PC.x, PC.y, PC.z, PC.w};

        float s[4], cc[4];
        #pragma unroll
        for (int j = 0; j < 4; ++j) __sincosf(tv[j], &s[j], &cc[j]);
        float sl, cl;
        __sincosf(TL, &sl, &cl);

        // vertical (up) interactions — up sincos from previous iteration's regs
        #pragma unroll
        for (int j = 0; j < 4; ++j)
            acc0 += cU[j] * cc[j] + sU[j] * s[j] * __cosf(pU[j] - pv[j]);

        // horizontal (left) interactions
        acc1 += cl * cc[0] + sl * s[0] * __cosf(PL - pv[0]);
        #pragma unroll
        for (int j = 1; j < 4; ++j)
            acc1 += cc[j-1] * cc[j] + s[j-1] * s[j] * __cosf(pv[j-1] - pv[j]);

        // current row becomes "up" for next row
        #pragma unroll
        for (int j = 0; j < 4; ++j) { sU[j] = s[j]; cU[j] = cc[j]; pU[j] = pv[j]; }
    }

    // ---- in-block reduction: 64-lane butterfly, then 16 waves via LDS
    float acc = acc0 + acc1;
    #pragma unroll
    for (int off = 32; off >= 1; off >>= 1)
        acc += __shfl_down(acc, off, 64);

    __shared__ float red[NWAVES];
    if (lane == 0) red[wave] = acc;
    __syncthreads();
    if (threadIdx.x == 0) {
        float ssum = 0.0f;
        #pragma unroll
        for (int w = 0; w < NWAVES; ++w) ssum += red[w];
        out[n] = ACTION_SHIFT_F - ssum;   // -BETA * sum + shift, BETA = 1
    }
}

extern "C" void kernel_launch(void* const* d_in, const int* in_sizes, int n_in,
                              void* d_out, int out_size, void* d_ws, size_t ws_size,
                              hipStream_t stream)
{
    const float* state = (const float*)d_in[0];
    // d_in[1] (shift table) is the fixed torus-neighbor map; computed analytically.
    float* out = (float*)d_out;

    action_kernel<<<dim3(N_STATES), dim3(THREADS), 0, stream>>>(state, out);
}